// Round 3
// baseline (838.780 us; speedup 1.0000x reference)
//
#include <hip/hip_runtime.h>
#include <cmath>

#define ENCD 128
#define DECD 128
#define INV_SQRT_D 0.08838834764831845f

// ---------------- init: zero the histogram counters ----------------
__global__ void init_counts(int* __restrict__ counts, int B) {
    int i = blockIdx.x * blockDim.x + threadIdx.x;
    if (i < B) counts[i] = 0;
}

// ---------------- qW = query[B,128] @ W[128,128] ----------------
__global__ void qw_gemm(const float* __restrict__ query, const float* __restrict__ W,
                        float* __restrict__ qW) {
    __shared__ float qs[8][DECD];
    const int t = threadIdx.x;
    const int row0 = blockIdx.x * 8;
    for (int i = t; i < 8 * DECD; i += 256)
        qs[i >> 7][i & 127] = query[(size_t)row0 * DECD + i];
    __syncthreads();
    const int c = t & 127;
    const int rh = t >> 7;  // 0..1
    float a0 = 0.f, a1 = 0.f, a2 = 0.f, a3 = 0.f;
    for (int k = 0; k < DECD; ++k) {
        const float w = W[k * ENCD + c];
        a0 += qs[rh * 4 + 0][k] * w;
        a1 += qs[rh * 4 + 1][k] * w;
        a2 += qs[rh * 4 + 2][k] * w;
        a3 += qs[rh * 4 + 3][k] * w;
    }
    qW[(size_t)(row0 + rh * 4 + 0) * ENCD + c] = a0;
    qW[(size_t)(row0 + rh * 4 + 1) * ENCD + c] = a1;
    qW[(size_t)(row0 + rh * 4 + 2) * ENCD + c] = a2;
    qW[(size_t)(row0 + rh * 4 + 3) * ENCD + c] = a3;
}

// ---------------- CSR build ----------------
__global__ void hist_kernel(const int* __restrict__ index, int* __restrict__ counts, int N) {
    int n4 = (blockIdx.x * blockDim.x + threadIdx.x) * 4;
    if (n4 + 3 < N) {
        const int4 v = *(const int4*)(index + n4);
        atomicAdd(&counts[v.x], 1);
        atomicAdd(&counts[v.y], 1);
        atomicAdd(&counts[v.z], 1);
        atomicAdd(&counts[v.w], 1);
    } else {
        for (int n = n4; n < N; ++n) atomicAdd(&counts[index[n]], 1);
    }
}

// single block, 1024 threads, scans up to 8192 counters (B=8192 here)
__global__ void scan_kernel(const int* __restrict__ counts, int* __restrict__ offsets,
                            int* __restrict__ cursor, int B) {
    __shared__ int tot[1024];
    const int t = threadIdx.x;
    int local[8];
    int s = 0;
#pragma unroll
    for (int i = 0; i < 8; ++i) {
        const int ci = t * 8 + i;
        local[i] = (ci < B) ? counts[ci] : 0;
        s += local[i];
    }
    tot[t] = s;
    __syncthreads();
    for (int off = 1; off < 1024; off <<= 1) {
        int v = (t >= off) ? tot[t - off] : 0;
        __syncthreads();
        tot[t] += v;
        __syncthreads();
    }
    int excl = tot[t] - s;
#pragma unroll
    for (int i = 0; i < 8; ++i) {
        const int ci = t * 8 + i;
        if (ci < B) { offsets[ci] = excl; cursor[ci] = excl; }
        excl += local[i];
    }
    if (t == 1023) offsets[B] = tot[1023];
}

__global__ void scatter_kernel(const int* __restrict__ index, int* __restrict__ cursor,
                               int* __restrict__ nodeids, int N) {
    int n4 = (blockIdx.x * blockDim.x + threadIdx.x) * 4;
    if (n4 + 3 < N) {
        const int4 v = *(const int4*)(index + n4);
        const int p0 = atomicAdd(&cursor[v.x], 1); nodeids[p0] = n4 + 0;
        const int p1 = atomicAdd(&cursor[v.y], 1); nodeids[p1] = n4 + 1;
        const int p2 = atomicAdd(&cursor[v.z], 1); nodeids[p2] = n4 + 2;
        const int p3 = atomicAdd(&cursor[v.w], 1); nodeids[p3] = n4 + 3;
    } else {
        for (int n = n4; n < N; ++n) {
            const int p = atomicAdd(&cursor[index[n]], 1);
            nodeids[p] = n;
        }
    }
}

// ---------------- main: one WAVE per segment, register-only online softmax ----------------
// 4 segments per 256-thread block (b = blockIdx*4 + wave). Zero LDS, zero
// barriers. Lane (r,g) with r=l>>3, g=l&7 owns row-slot r and the 16 columns
// {i*32 + g*4 .. +3 | i=0..3} (so each global_load_dwordx4 has 8 consecutive
// lanes reading a contiguous 128 B run of a row: perfectly coalesced).
//
// Key change vs R2: the accumulator stays in the SAME lane layout as the
// loaded row fragment (acc[i] += pe * CUR[i]; pe is lane-local after the
// score butterfly) — no per-iteration LDS transpose at all. The cross-row-slot
// reduction (sum over r) happens ONCE at the end via a 3-step shfl_xor
// butterfly over masks 8/16/32. Online-softmax rescale is a rare wave-uniform
// branch (only when the running max actually increases). Next-iteration rows
// and nodeids are register-prefetched so scattered HBM latency hides under
// the ~15-iteration per-wave loop.
__device__ __forceinline__ float dot4(const float4 a, const float4 b) {
    return a.x * b.x + a.y * b.y + a.z * b.z + a.w * b.w;
}

#define SEG_ITER(CUR, NXT, P)                                                  \
  {                                                                            \
    float pd = dot4(CUR[0], q4[0]) + dot4(CUR[1], q4[1]) +                     \
               dot4(CUR[2], q4[2]) + dot4(CUR[3], q4[3]);                      \
    pd += __shfl_xor(pd, 1);   /* sum across g (col groups) */                 \
    pd += __shfl_xor(pd, 2);                                                   \
    pd += __shfl_xor(pd, 4);                                                   \
    const float sc = ((P) + r < end) ? pd * INV_SQRT_D : -INFINITY;            \
    float mc = sc;             /* max across r (row slots) -> wave-uniform */  \
    mc = fmaxf(mc, __shfl_xor(mc, 8));                                         \
    mc = fmaxf(mc, __shfl_xor(mc, 16));                                        \
    mc = fmaxf(mc, __shfl_xor(mc, 32));                                        \
    if (mc > m) {              /* wave-uniform branch; rare after warmup */    \
      const float scale = __expf(m - mc);  /* first iter: exp(-inf)=0 */       \
      _Pragma("unroll")                                                        \
      for (int i = 0; i < 16; ++i) acc[i] *= scale;                            \
      lacc *= scale;                                                           \
      m = mc;                                                                  \
    }                                                                          \
    const float pe = __expf(sc - m);       /* invalid rows: exp(-inf)=0 */     \
    if ((P) + 8 < end) {       /* wave-uniform prefetch guard */               \
      const float* vp = values + (size_t)nid_next * ENCD + g4;                 \
      NXT[0] = *(const float4*)(vp + 0);                                       \
      NXT[1] = *(const float4*)(vp + 32);                                      \
      NXT[2] = *(const float4*)(vp + 64);                                      \
      NXT[3] = *(const float4*)(vp + 96);                                      \
      const int nn = (P) + 16 + r;                                             \
      nid_next = nodeids[(nn < end) ? nn : beg];                               \
    }                                                                          \
    _Pragma("unroll")                                                          \
    for (int i = 0; i < 4; ++i) {  /* lane-local accumulate: no LDS, no shfl */\
      acc[i * 4 + 0] += pe * CUR[i].x;                                         \
      acc[i * 4 + 1] += pe * CUR[i].y;                                         \
      acc[i * 4 + 2] += pe * CUR[i].z;                                         \
      acc[i * 4 + 3] += pe * CUR[i].w;                                         \
    }                                                                          \
    lacc += pe;                                                                \
  }

__global__ __launch_bounds__(256) void seg_attn(
    const float* __restrict__ values, const float* __restrict__ qW,
    const int* __restrict__ offsets, const int* __restrict__ nodeids,
    float* __restrict__ out) {
    const int t = threadIdx.x;
    const int w = t >> 6;              // wave 0..3
    const int b = blockIdx.x * 4 + w;  // segment owned by this wave
    const int l = t & 63;
    const int r = l >> 3;              // row slot 0..7
    const int g4 = (l & 7) * 4;        // float offset of this lane's col chunk

    const int beg = offsets[b];
    const int end = offsets[b + 1];

    // q fragments matching the lane's column ownership
    float4 q4[4];
    const float* qp = qW + (size_t)b * ENCD + g4;
    q4[0] = *(const float4*)(qp + 0);
    q4[1] = *(const float4*)(qp + 32);
    q4[2] = *(const float4*)(qp + 64);
    q4[3] = *(const float4*)(qp + 96);

    float acc[16];
#pragma unroll
    for (int i = 0; i < 16; ++i) acc[i] = 0.f;
    float lacc = 0.f;
    float m = -INFINITY;
    float4 va[4], vb[4];
    int nid_next = 0;

    int p = beg;
    if (p < end) {
        // prologue: rows for iter 0, nodeids for iter 1
        const int pp = p + r;
        const int nid0 = nodeids[(pp < end) ? pp : beg];
        const float* vp = values + (size_t)nid0 * ENCD + g4;
        va[0] = *(const float4*)(vp + 0);
        va[1] = *(const float4*)(vp + 32);
        va[2] = *(const float4*)(vp + 64);
        va[3] = *(const float4*)(vp + 96);
        const int np = p + 8 + r;
        nid_next = nodeids[(np < end) ? np : beg];
        while (true) {
            SEG_ITER(va, vb, p);
            p += 8;
            if (p >= end) break;
            SEG_ITER(vb, va, p);
            p += 8;
            if (p >= end) break;
        }
    }

    // one-time cross-row-slot reduction (sum over r: masks 8/16/32)
#pragma unroll
    for (int i = 0; i < 16; ++i) {
        acc[i] += __shfl_xor(acc[i], 8);
        acc[i] += __shfl_xor(acc[i], 16);
        acc[i] += __shfl_xor(acc[i], 32);
    }
    lacc += __shfl_xor(lacc, 8);
    lacc += __shfl_xor(lacc, 16);
    lacc += __shfl_xor(lacc, 32);

    if (r == 0) {  // lanes 0..7 write the 128 output floats, coalesced
        const float inv = (lacc > 0.f) ? 1.f / lacc : 0.f;
        float* op = out + (size_t)b * ENCD + g4;
#pragma unroll
        for (int i = 0; i < 4; ++i) {
            float4 o;
            o.x = acc[i * 4 + 0] * inv;
            o.y = acc[i * 4 + 1] * inv;
            o.z = acc[i * 4 + 2] * inv;
            o.w = acc[i * 4 + 3] * inv;
            *(float4*)(op + i * 32) = o;
        }
    }
}

extern "C" void kernel_launch(void* const* d_in, const int* in_sizes, int n_in,
                              void* d_out, int out_size, void* d_ws, size_t ws_size,
                              hipStream_t stream) {
    const float* query  = (const float*)d_in[0];   // [B,128]
    const float* values = (const float*)d_in[1];   // [N,128]
    const int*   index  = (const int*)d_in[2];     // [N]
    const float* W      = (const float*)d_in[3];   // [128,128]
    float* out = (float*)d_out;                    // [B,128]

    const int B = in_sizes[0] / DECD;   // 8192
    const int N = in_sizes[2];          // 1,000,000

    // workspace carve (~8.3 MB)
    float* qW      = (float*)d_ws;                    // B*128 floats
    int*   nodeids = (int*)(qW + (size_t)B * ENCD);   // N ints
    int*   counts  = nodeids + N;                     // B
    int*   offsets = counts + B;                      // B+1
    int*   cursor  = offsets + B + 1;                 // B

    init_counts<<<(B + 255) / 256, 256, 0, stream>>>(counts, B);
    qw_gemm<<<B / 8, 256, 0, stream>>>(query, W, qW);
    hist_kernel<<<(N / 4 + 255) / 256, 256, 0, stream>>>(index, counts, N);
    scan_kernel<<<1, 1024, 0, stream>>>(counts, offsets, cursor, B);
    scatter_kernel<<<(N / 4 + 255) / 256, 256, 0, stream>>>(index, cursor, nodeids, N);
    seg_attn<<<B / 4, 256, 0, stream>>>(values, qW, offsets, nodeids, out);
}